// Round 5
// baseline (957.296 us; speedup 1.0000x reference)
//
#include <hip/hip_runtime.h>

#define CIN 32
#define COUT 64
#define OD0 100
#define OD1 100
#define OD2 8
#define NUMOUT (2 * OD0 * OD1 * OD2)   // 160000
#define NTILE (NUMOUT / 16)            // 10000
#define NBUCK (NTILE * 32)             // 320000
#define CHUNK 1024
#define NCHUNK ((NBUCK + CHUNK - 1) / CHUNK)   // 313
#define NWPK (27 * 64 * 32)            // 55296 bf16
#define PPB (NWPK / 256)               // 216 prepack blocks

typedef short short8 __attribute__((ext_vector_type(8)));
typedef float f32x4 __attribute__((ext_vector_type(4)));

__device__ __forceinline__ unsigned short f2bf(float f) {
    unsigned u = __float_as_uint(f);
    u += 0x7FFFu + ((u >> 16) & 1u);      // RNE
    return (unsigned short)(u >> 16);
}
__device__ __forceinline__ unsigned pk2(float a, float b) {
    return (unsigned)f2bf(a) | ((unsigned)f2bf(b) << 16);
}

// ---------- tap enumeration (stride-2, pad-1: <=2 taps per dim) ----------

template <typename F>
__device__ __forceinline__ void for_taps(int4 c, F f) {
    int bb = c.x, pz = c.y, py = c.z, px = c.w;
    int oz[2], ozo[2], nz = 0, oy[2], oyo[2], ny = 0, ox[2], oxo[2], nx = 0;
#pragma unroll
    for (int o = 0; o < 3; o++) {
        int num = pz + 1 - o;
        if (num >= 0 && !(num & 1) && (num >> 1) < OD0) { oz[nz] = num >> 1; ozo[nz] = o; nz++; }
        num = py + 1 - o;
        if (num >= 0 && !(num & 1) && (num >> 1) < OD1) { oy[ny] = num >> 1; oyo[ny] = o; ny++; }
        num = px + 1 - o;
        if (num >= 0 && !(num & 1) && (num >> 1) < OD2) { ox[nx] = num >> 1; oxo[nx] = o; nx++; }
    }
    for (int a = 0; a < nz; a++)
        for (int b = 0; b < ny; b++)
            for (int d = 0; d < nx; d++) {
                int cell = ((bb * OD0 + oz[a]) * OD1 + oy[b]) * OD2 + ox[d];
                int off = (ozo[a] * 3 + oyo[b]) * 3 + oxo[d];
                f(cell, off);
            }
}

// ---------- parallel two-level radix select (one full 256-thread block) ----------

__device__ void selectDev(const int* __restrict__ hist, int rank, int* __restrict__ out) {
    __shared__ int p1[256];
    __shared__ int sc[256];
    __shared__ int wT, wB;
    int t = threadIdx.x;
    int mySum = 0;
    if (t < 256) {
        const int* h = hist + t * 256;
        for (int j = 0; j < 256; j++) mySum += h[j];
        sc[t] = mySum;
        p1[t] = mySum;
    }
    __syncthreads();
    for (int d = 1; d < 256; d <<= 1) {
        int a = 0;
        if (t < 256 && t >= d) a = sc[t - d];
        __syncthreads();
        if (t < 256) sc[t] += a;
        __syncthreads();
    }
    if (t < 256) {
        int excl = sc[t] - p1[t];
        if (rank >= excl && rank < sc[t]) { wT = t; wB = excl; }
    }
    __syncthreads();
    int hiT = wT, r2 = rank - wB;
    int hv = 0;
    if (t < 256) {
        hv = hist[hiT * 256 + t];
        sc[t] = hv;
    }
    __syncthreads();
    for (int d = 1; d < 256; d <<= 1) {
        int a = 0;
        if (t < 256 && t >= d) a = sc[t - d];
        __syncthreads();
        if (t < 256) sc[t] += a;
        __syncthreads();
    }
    if (t < 256) {
        int excl = sc[t] - hv;
        if (r2 >= excl && r2 < sc[t]) { out[0] = hiT * 256 + t; out[1] = r2 - excl; }
    }
}

// ---------- K1: W-prepack (blocks 0..215) + bucket counts + hi-16 histogram ----------

__global__ void __launch_bounds__(256)
count_kernel(const float* __restrict__ mask, const int* __restrict__ coors, int n,
             int* __restrict__ histHi, unsigned* __restrict__ cnt,
             const float* __restrict__ W, unsigned short* __restrict__ wpk) {
    int i = blockIdx.x * 256 + threadIdx.x;
    if (blockIdx.x < PPB) {
        int j = i & 7, b = (i >> 3) & 3, lane = (i >> 5) & 63, off = i >> 11;
        int k = ((lane >> 4) << 3) + j;
        int cout = (b << 4) + (lane & 15);
        wpk[i] = f2bf(W[off * (CIN * COUT) + k * COUT + cout]);
    }
    if (i >= n) return;
    atomicAdd(&histHi[__float_as_uint(mask[i]) >> 16], 1);
    int4 c = ((const int4*)coors)[i];
    for_taps(c, [&](int cell, int off) {
        atomicAdd(&cnt[((unsigned)(cell >> 4) << 5) | (unsigned)off], 1u);
    });
}

// ---------- K2: per-chunk scan; last-finisher block: chunk scan + sentinel + select1 ----------

__global__ void __launch_bounds__(256)
scanA_kernel(const unsigned* __restrict__ cnt, unsigned* __restrict__ base,
             unsigned* __restrict__ chunkSum, unsigned* __restrict__ chunkBase,
             const int* __restrict__ histHi, int rank, int* __restrict__ sel,
             unsigned* __restrict__ done) {
    __shared__ unsigned s[256];
    __shared__ unsigned cs[NCHUNK + 1];
    __shared__ int lastFlag;
    int b = blockIdx.x, t = threadIdx.x;
    int i0 = b * CHUNK + t * 4;
    uint4 v = make_uint4(0, 0, 0, 0);
    if (i0 + 3 < NBUCK) v = *(const uint4*)(cnt + i0);
    else {
        if (i0 + 0 < NBUCK) v.x = cnt[i0 + 0];
        if (i0 + 1 < NBUCK) v.y = cnt[i0 + 1];
        if (i0 + 2 < NBUCK) v.z = cnt[i0 + 2];
        if (i0 + 3 < NBUCK) v.w = cnt[i0 + 3];
    }
    unsigned tsum = v.x + v.y + v.z + v.w;
    s[t] = tsum;
    __syncthreads();
    for (int d = 1; d < 256; d <<= 1) {
        unsigned a = (t >= d) ? s[t - d] : 0u;
        __syncthreads();
        s[t] += a;
        __syncthreads();
    }
    unsigned excl = s[t] - tsum;
    if (t == 255) chunkSum[b] = s[255];
    if (i0 + 0 < NBUCK) base[i0 + 0] = excl;
    if (i0 + 1 < NBUCK) base[i0 + 1] = excl + v.x;
    if (i0 + 2 < NBUCK) base[i0 + 2] = excl + v.x + v.y;
    if (i0 + 3 < NBUCK) base[i0 + 3] = excl + v.x + v.y + v.z;

    __threadfence();
    if (t == 0) lastFlag = (atomicAdd(done, 1u) == (unsigned)(NCHUNK - 1)) ? 1 : 0;
    __syncthreads();
    if (!lastFlag) return;
    __threadfence();
    for (int j = t; j < NCHUNK; j += 256) cs[j + 1] = chunkSum[j];
    if (t == 0) cs[0] = 0;
    __syncthreads();
    if (t == 0) {
        for (int j = 1; j <= NCHUNK; j++) cs[j] += cs[j - 1];
        base[NBUCK] = cs[NCHUNK];          // sentinel: total pair count
    }
    __syncthreads();
    for (int j = t; j < NCHUNK; j += 256) chunkBase[j] = cs[j];
    selectDev(histHi, rank, sel);
}

// ---------- K3: add-back + cursor init + lo-16 histogram ----------

__global__ void __launch_bounds__(256)
scanC_kernel(unsigned* __restrict__ base, unsigned* __restrict__ cursor,
             const unsigned* __restrict__ chunkBase,
             const float* __restrict__ mask, int n,
             const int* __restrict__ sel, int* __restrict__ histLo) {
    int i = blockIdx.x * 256 + threadIdx.x;
    if (i < NBUCK) {
        unsigned v = base[i] + chunkBase[i >> 10];
        base[i] = v;
        cursor[i] = v;
    }
    if (i < n) {
        unsigned bits = __float_as_uint(mask[i]);
        if ((int)(bits >> 16) == sel[0]) atomicAdd(&histLo[bits & 0xFFFFu], 1);
    }
}

// ---------- K4 (full): im2col fill — bf16 A-rows + ci + maxMask; extra block = select2 ----------

__global__ void __launch_bounds__(256)
fill_full_kernel(const float* __restrict__ mask, const int* __restrict__ coors,
                 const float* __restrict__ feat, int n, int nBlk,
                 const int* __restrict__ selIn, int* __restrict__ selOut,
                 const int* __restrict__ histLo,
                 unsigned* __restrict__ cursor, unsigned short* __restrict__ arow,
                 unsigned char* __restrict__ cib, unsigned* __restrict__ mm,
                 unsigned pcap) {
    if ((int)blockIdx.x == nBlk) { selectDev(histLo, selIn[1], selOut); return; }
    int i = blockIdx.x * 256 + threadIdx.x;
    if (i >= n) return;
    unsigned mbits = __float_as_uint(mask[i]);
    const float4* fp = (const float4*)(feat + ((size_t)i << 5));
    uint4 u[4];
#pragma unroll
    for (int q = 0; q < 4; q++) {
        float4 a = fp[2 * q], b = fp[2 * q + 1];
        u[q].x = pk2(a.x, a.y); u[q].y = pk2(a.z, a.w);
        u[q].z = pk2(b.x, b.y); u[q].w = pk2(b.z, b.w);
    }
    int4 c = ((const int4*)coors)[i];
    for_taps(c, [&](int cell, int off) {
        unsigned key = ((unsigned)(cell >> 4) << 5) | (unsigned)off;
        unsigned pos = atomicAdd(&cursor[key], 1u);
        if (pos < pcap) {
            uint4* dst = (uint4*)(arow + ((size_t)pos << 5));
            dst[0] = u[0]; dst[1] = u[1]; dst[2] = u[2]; dst[3] = u[3];
            cib[pos] = (unsigned char)(cell & 15);
        }
        atomicMax(&mm[cell], mbits);
    });
}

// ---------- K4 (fallback): pair-index fill ----------

__global__ void __launch_bounds__(256)
fill_legacy_kernel(const float* __restrict__ mask, const int* __restrict__ coors,
                   int n, int nBlk,
                   const int* __restrict__ selIn, int* __restrict__ selOut,
                   const int* __restrict__ histLo,
                   unsigned* __restrict__ cursor, unsigned* __restrict__ pairs,
                   unsigned* __restrict__ mm, unsigned pcap) {
    if ((int)blockIdx.x == nBlk) { selectDev(histLo, selIn[1], selOut); return; }
    int i = blockIdx.x * 256 + threadIdx.x;
    if (i >= n) return;
    unsigned mbits = __float_as_uint(mask[i]);
    int4 c = ((const int4*)coors)[i];
    for_taps(c, [&](int cell, int off) {
        unsigned key = ((unsigned)(cell >> 4) << 5) | (unsigned)off;
        unsigned pos = atomicAdd(&cursor[key], 1u);
        if (pos < pcap) pairs[pos] = ((unsigned)i << 4) | (unsigned)(cell & 15);
        atomicMax(&mm[cell], mbits);
    });
}

// ---------- K5 (full): streaming MFMA gather — zero indirection ----------

__global__ void __launch_bounds__(256, 4)
gather_full_kernel(const unsigned short* __restrict__ arow,
                   const unsigned char* __restrict__ cib,
                   const unsigned short* __restrict__ wpk,
                   const unsigned* __restrict__ mm,
                   const int* __restrict__ sel,
                   const unsigned* __restrict__ bucketBase,
                   float* __restrict__ out, unsigned rowCap) {
    __shared__ float accS[4][16 * 64];
    int t = threadIdx.x, wv = t >> 6, lane = t & 63;
    int l16 = lane & 15, quad = lane >> 4;
    float* acc = accS[wv];
    int tile = blockIdx.x * 4 + wv;

    float4* accv = (float4*)acc;
#pragma unroll
    for (int q = 0; q < 4; q++) accv[q * 64 + lane] = make_float4(0.f, 0.f, 0.f, 0.f);

    unsigned bbv = (lane < 28) ? bucketBase[((unsigned)tile << 5) + lane] : 0u;
    unsigned nbv = __shfl(bbv, (lane + 1) & 63);
    unsigned long long neB = __ballot(lane < 27 && nbv > bbv);
    unsigned offMask = (unsigned)(neB & 0x7FFFFFFull);

    unsigned P = bucketBase[NBUCK];
    unsigned cap = P < rowCap ? P : rowCap;
    unsigned lastRow = cap ? cap - 1u : 0u;

    if (offMask) {
        int curOff = __ffs(offMask) - 1; offMask &= offMask - 1;
        int nextOff = 27;
        if (offMask) { nextOff = __ffs(offMask) - 1; offMask &= offMask - 1; }

        unsigned i = __shfl(bbv, 0);
        unsigned eCur = __shfl(bbv, curOff + 1);

        const unsigned short* wb = wpk + (size_t)(curOff * 64 + lane) * 32;
        short8 Bc0 = *(const short8*)(wb + 0);
        short8 Bc1 = *(const short8*)(wb + 8);
        short8 Bc2 = *(const short8*)(wb + 16);
        short8 Bc3 = *(const short8*)(wb + 24);
        short8 Bn0 = Bc0, Bn1 = Bc1, Bn2 = Bc2, Bn3 = Bc3;
        if (nextOff < 27) {
            const unsigned short* wn = wpk + (size_t)(nextOff * 64 + lane) * 32;
            Bn0 = *(const short8*)(wn + 0);
            Bn1 = *(const short8*)(wn + 8);
            Bn2 = *(const short8*)(wn + 16);
            Bn3 = *(const short8*)(wn + 24);
        }
        unsigned rA = i + (unsigned)l16; if (rA > lastRow) rA = lastRow;
        short8 Ac = *(const short8*)(arow + ((size_t)rA << 5) + (quad << 3));

        for (;;) {
            unsigned cnt = eCur - i; if (cnt > 16u) cnt = 16u;
            unsigned nextI = i + cnt;
            unsigned rN = nextI + (unsigned)l16; if (rN > lastRow) rN = lastRow;
            short8 An = *(const short8*)(arow + ((size_t)rN << 5) + (quad << 3));

            unsigned rb = i + (unsigned)(quad << 2);
            unsigned r0 = rb + 0 > lastRow ? lastRow : rb + 0;
            unsigned r1 = rb + 1 > lastRow ? lastRow : rb + 1;
            unsigned r2 = rb + 2 > lastRow ? lastRow : rb + 2;
            unsigned r3 = rb + 3 > lastRow ? lastRow : rb + 3;
            unsigned cv0 = cib[r0], cv1 = cib[r1], cv2 = cib[r2], cv3 = cib[r3];

            f32x4 z = {0.f, 0.f, 0.f, 0.f};
            f32x4 c0 = __builtin_amdgcn_mfma_f32_16x16x32_bf16(Ac, Bc0, z, 0, 0, 0);
            f32x4 c1 = __builtin_amdgcn_mfma_f32_16x16x32_bf16(Ac, Bc1, z, 0, 0, 0);
            f32x4 c2 = __builtin_amdgcn_mfma_f32_16x16x32_bf16(Ac, Bc2, z, 0, 0, 0);
            f32x4 c3 = __builtin_amdgcn_mfma_f32_16x16x32_bf16(Ac, Bc3, z, 0, 0, 0);

            unsigned ri = (unsigned)(quad << 2);
            float* ap;
            if (ri + 0 < cnt) { ap = acc + (cv0 << 6) + l16; atomicAdd(ap, c0[0]); atomicAdd(ap + 16, c1[0]); atomicAdd(ap + 32, c2[0]); atomicAdd(ap + 48, c3[0]); }
            if (ri + 1 < cnt) { ap = acc + (cv1 << 6) + l16; atomicAdd(ap, c0[1]); atomicAdd(ap + 16, c1[1]); atomicAdd(ap + 32, c2[1]); atomicAdd(ap + 48, c3[1]); }
            if (ri + 2 < cnt) { ap = acc + (cv2 << 6) + l16; atomicAdd(ap, c0[2]); atomicAdd(ap + 16, c1[2]); atomicAdd(ap + 32, c2[2]); atomicAdd(ap + 48, c3[2]); }
            if (ri + 3 < cnt) { ap = acc + (cv3 << 6) + l16; atomicAdd(ap, c0[3]); atomicAdd(ap + 16, c1[3]); atomicAdd(ap + 32, c2[3]); atomicAdd(ap + 48, c3[3]); }

            if (nextI >= eCur) {
                if (nextOff >= 27) break;
                curOff = nextOff;
                eCur = __shfl(bbv, curOff + 1);
                Bc0 = Bn0; Bc1 = Bn1; Bc2 = Bn2; Bc3 = Bn3;
                nextOff = 27;
                if (offMask) {
                    nextOff = __ffs(offMask) - 1; offMask &= offMask - 1;
                    const unsigned short* wn = wpk + (size_t)(nextOff * 64 + lane) * 32;
                    Bn0 = *(const short8*)(wn + 0);
                    Bn1 = *(const short8*)(wn + 8);
                    Bn2 = *(const short8*)(wn + 16);
                    Bn3 = *(const short8*)(wn + 24);
                }
            }
            Ac = An; i = nextI;
        }
    }

    unsigned thrBits = (((unsigned)sel[0]) << 16) | (unsigned)sel[2];
    bool kp = (lane < 16) && (mm[tile * 16 + (lane & 15)] >= thrBits);
    unsigned keepM = (unsigned)(__ballot(kp) & 0xFFFFull);

    float* outp = out + ((size_t)tile << 10);
#pragma unroll
    for (int ci = 0; ci < 16; ci++) {
        float v = acc[(ci << 6) + lane];
        outp[(ci << 6) + lane] = ((keepM >> ci) & 1u) ? v : 0.f;
    }
}

// ---------- K5 (fallback): R4-style indirect gather ----------

__global__ void __launch_bounds__(256, 4)
gather_legacy_kernel(const float* __restrict__ feat, const unsigned short* __restrict__ wpk,
                     const unsigned* __restrict__ mm, const int* __restrict__ sel,
                     const unsigned* __restrict__ bucketBase, const unsigned* __restrict__ pairs,
                     float* __restrict__ out) {
    __shared__ float accS[4][16 * 64];
    int t = threadIdx.x, wv = t >> 6, lane = t & 63;
    int l16 = lane & 15, quad = lane >> 4;
    float* acc = accS[wv];
    int tile = blockIdx.x * 4 + wv;
    float4* accv = (float4*)acc;
#pragma unroll
    for (int q = 0; q < 4; q++) accv[q * 64 + lane] = make_float4(0.f, 0.f, 0.f, 0.f);

    unsigned i = bucketBase[(unsigned)tile << 5];
    unsigned lastIdx = bucketBase[NBUCK];

#pragma unroll 1
    for (int off = 0; off < 27; off++) {
        unsigned end = bucketBase[((unsigned)tile << 5) + off + 1];
        if (i >= end) continue;
        const unsigned short* wb = wpk + ((size_t)(off * 64 + lane)) * 32;
        short8 B0 = *(const short8*)(wb + 0);
        short8 B1 = *(const short8*)(wb + 8);
        short8 B2 = *(const short8*)(wb + 16);
        short8 B3 = *(const short8*)(wb + 24);
        do {
            unsigned c = end - i;
            if (c > 16u) c = 16u;
            unsigned idx = i + (unsigned)l16;
            if (idx >= lastIdx) idx = lastIdx - 1;
            unsigned e = pairs[idx];
            if ((unsigned)l16 >= c) e = 0xFFFFFFFFu;
            unsigned p = (e != 0xFFFFFFFFu) ? (e >> 4) : 0u;
            const float4* fp = (const float4*)(feat + ((size_t)p << 5) + (quad << 3));
            float4 fa = fp[0], fb = fp[1];
            short8 A;
            A[0] = (short)f2bf(fa.x); A[1] = (short)f2bf(fa.y);
            A[2] = (short)f2bf(fa.z); A[3] = (short)f2bf(fa.w);
            A[4] = (short)f2bf(fb.x); A[5] = (short)f2bf(fb.y);
            A[6] = (short)f2bf(fb.z); A[7] = (short)f2bf(fb.w);
            f32x4 z = {0.f, 0.f, 0.f, 0.f};
            f32x4 c0 = __builtin_amdgcn_mfma_f32_16x16x32_bf16(A, B0, z, 0, 0, 0);
            f32x4 c1 = __builtin_amdgcn_mfma_f32_16x16x32_bf16(A, B1, z, 0, 0, 0);
            f32x4 c2 = __builtin_amdgcn_mfma_f32_16x16x32_bf16(A, B2, z, 0, 0, 0);
            f32x4 c3 = __builtin_amdgcn_mfma_f32_16x16x32_bf16(A, B3, z, 0, 0, 0);
#pragma unroll
            for (int r = 0; r < 4; r++) {
                unsigned es = __shfl(e, quad * 4 + r);
                if (es != 0xFFFFFFFFu) {
                    float* ap = acc + ((es & 15u) << 6) + l16;
                    atomicAdd(ap + 0, c0[r]);
                    atomicAdd(ap + 16, c1[r]);
                    atomicAdd(ap + 32, c2[r]);
                    atomicAdd(ap + 48, c3[r]);
                }
            }
            i += c;
        } while (i < end);
    }

    unsigned thrBits = (((unsigned)sel[0]) << 16) | (unsigned)sel[2];
    bool kp = (lane < 16) && (mm[tile * 16 + (lane & 15)] >= thrBits);
    unsigned keepM = (unsigned)(__ballot(kp) & 0xFFFFull);
    float* outp = out + ((size_t)tile << 10);
#pragma unroll
    for (int ci = 0; ci < 16; ci++) {
        float v = acc[(ci << 6) + lane];
        outp[(ci << 6) + lane] = ((keepM >> ci) & 1u) ? v : 0.f;
    }
}

// ---------- host ----------

extern "C" void kernel_launch(void* const* d_in, const int* in_sizes, int n_in,
                              void* d_out, int out_size, void* d_ws, size_t ws_size,
                              hipStream_t stream) {
    const float* feat  = (const float*)d_in[0];   // (N, 32) f32
    const int*   coors = (const int*)d_in[1];     // (N, 4)  i32
    const float* mask  = (const float*)d_in[2];   // (N,)    f32
    const float* W     = (const float*)d_in[3];   // (3,3,3,32,64) f32

    int n = in_sizes[2];
    int rank = (int)(n * 0.5);

    char* ws = (char*)d_ws;
    size_t o = 0;
    int* histHi = (int*)(ws + o);              o += 65536 * 4;
    int* histLo = (int*)(ws + o);              o += 65536 * 4;
    int* sel    = (int*)(ws + o);              o += 256;     // sel[0..3]; done = sel[8]
    unsigned* cnt = (unsigned*)(ws + o);       o += (size_t)NBUCK * 4;
    unsigned* mm  = (unsigned*)(ws + o);       o += (size_t)NUMOUT * 4;
    size_t memsetBytes = o;
    o = (o + 15) & ~(size_t)15;
    unsigned* base = (unsigned*)(ws + o);      o += ((size_t)NBUCK + 4) * 4;
    unsigned* cursor = (unsigned*)(ws + o);    o += (size_t)NBUCK * 4;
    unsigned* chunkSum = (unsigned*)(ws + o);  o += 512 * 4;
    unsigned* chunkBase = (unsigned*)(ws + o); o += 512 * 4;
    unsigned short* wpk = (unsigned short*)(ws + o); o += (size_t)NWPK * 2;
    o = (o + 63) & ~(size_t)63;
    size_t fixedEnd = o;
    unsigned* done = (unsigned*)(sel + 8);

    size_t avail = (ws_size > fixedEnd) ? (ws_size - fixedEnd) : 0;
    size_t maxPairs = (size_t)n * 8;
    size_t pcapFull = avail / 65;              // 64 B A-row + 1 B ci per pair
    if (pcapFull > maxPairs) pcapFull = maxPairs;
    bool full = pcapFull >= 1600000;           // expected ~1.35M pairs + 18% margin

    unsigned short* arow = (unsigned short*)(ws + fixedEnd);
    unsigned char* cib = (unsigned char*)(ws + fixedEnd + pcapFull * 64);
    unsigned* pairs = (unsigned*)(ws + fixedEnd);
    size_t pcapLegacy = avail / 4;
    if (pcapLegacy > maxPairs) pcapLegacy = maxPairs;

    hipMemsetAsync(d_ws, 0, memsetBytes, stream);

    const int blk = 256;
    int gN = (n + blk - 1) / blk;              // 1563; also covers NBUCK (320000/256)
    count_kernel<<<gN, blk, 0, stream>>>(mask, coors, n, histHi, cnt, W, wpk);
    scanA_kernel<<<NCHUNK, blk, 0, stream>>>(cnt, base, chunkSum, chunkBase,
                                             histHi, rank, sel, done);
    scanC_kernel<<<gN, blk, 0, stream>>>(base, cursor, chunkBase, mask, n, sel, histLo);
    if (full) {
        fill_full_kernel<<<gN + 1, blk, 0, stream>>>(mask, coors, feat, n, gN,
                                                     sel, sel + 2, histLo, cursor,
                                                     arow, cib, mm, (unsigned)pcapFull);
        gather_full_kernel<<<NTILE / 4, blk, 0, stream>>>(arow, cib, wpk, mm, sel,
                                                          base, (float*)d_out,
                                                          (unsigned)pcapFull);
    } else {
        fill_legacy_kernel<<<gN + 1, blk, 0, stream>>>(mask, coors, n, gN,
                                                       sel, sel + 2, histLo, cursor,
                                                       pairs, mm, (unsigned)pcapLegacy);
        gather_legacy_kernel<<<NTILE / 4, blk, 0, stream>>>(feat, wpk, mm, sel,
                                                            base, pairs, (float*)d_out);
    }
}